// Round 8
// baseline (215.382 us; speedup 1.0000x reference)
//
#include <hip/hip_runtime.h>
#include <stdint.h>

#define N_V   4096
#define T_PER 4
#define NT    16384
#define D_K   256
#define SCALE 10.0f   // 1/temperature
#define LOG2E 1.44269504088896340736f
#define LN2   0.69314718055994530942f

#if defined(__has_builtin)
#if __has_builtin(__builtin_amdgcn_exp2f)
#define EXP2F(x) __builtin_amdgcn_exp2f(x)
#endif
#endif
#ifndef EXP2F
#define EXP2F(x) exp2f(x)
#endif

typedef __bf16 bf16x8 __attribute__((ext_vector_type(8)));
typedef float  f32x4  __attribute__((ext_vector_type(4)));

__device__ __forceinline__ unsigned short f2bf(float f) {
  uint32_t u = __float_as_uint(f);
  u = (u + 0x7fffu + ((u >> 16) & 1u)) >> 16;   // RNE
  return (unsigned short)u;
}

// ---------------- A: fused convert + diagonal dots (reads v,t exactly once) ---------------
// A-side bf16 carries SCALE*LOG2E so GEMM scores come out in log2 domain.
__global__ void k_prep(const float* __restrict__ v, const float* __restrict__ t,
                       unsigned short* __restrict__ Abf, unsigned short* __restrict__ Bbf,
                       float* __restrict__ thr, float* __restrict__ nom,
                       float* __restrict__ out) {
  const int tid = threadIdx.x, l = tid & 63, w = tid >> 6;
  const int i = blockIdx.x * 4 + w;            // one wave per video
  if (blockIdx.x == 0 && tid < 5) out[tid] = 0.0f;
  const float AS = SCALE * LOG2E;

  float4 a = ((const float4*)(v + (size_t)i * D_K))[l];
  ushort4 oa;
  oa.x = f2bf(a.x * AS); oa.y = f2bf(a.y * AS);
  oa.z = f2bf(a.z * AS); oa.w = f2bf(a.w * AS);
  ((ushort4*)(Abf + (size_t)i * D_K))[l] = oa;

  float tv[T_PER];
#pragma unroll
  for (int tt = 0; tt < T_PER; ++tt) {
    float4 b = ((const float4*)(t + (size_t)(i * T_PER + tt) * D_K))[l];
    ushort4 ob;
    ob.x = f2bf(b.x); ob.y = f2bf(b.y); ob.z = f2bf(b.z); ob.w = f2bf(b.w);
    ((ushort4*)(Bbf + (size_t)(i * T_PER + tt) * D_K))[l] = ob;
    float d = a.x * b.x + a.y * b.y + a.z * b.z + a.w * b.w;
#pragma unroll
    for (int s = 1; s < 64; s <<= 1) d += __shfl_xor(d, s);
    tv[tt] = d * SCALE;                        // natural-domain score
  }
  if (l == 0) {
    ((float4*)thr)[i] = make_float4(tv[0] * LOG2E, tv[1] * LOG2E,
                                    tv[2] * LOG2E, tv[3] * LOG2E);
    float m = fmaxf(fmaxf(tv[0], tv[1]), fmaxf(tv[2], tv[3]));
    float e = __expf(tv[0] - m) + __expf(tv[1] - m) + __expf(tv[2] - m) + __expf(tv[3] - m);
    nom[i] = m + __logf(e);
  }
}

// ---------------- B: small-footprint GEMM (32x128 tile, 5 waves/SIMD) ----------------------
// Wave = 32 rows x 32 cols: acc = 16 VGPRs (vs 64 in r7) -> __launch_bounds__(256,5) caps
// arch VGPRs at 102 -> ~20 waves/CU (3x r7's 6.5). Rationale: r1..r7 all plateau 126-165us
// with VALU 40% / MFMA 11% / occ 20% -- latency-bound; epilogue VALU (~121K cyc/CU) is the
// floor and needs wave overlap, not staging tweaks. A (32x256,16KB) staged once via
// global_load_lds + XOR swizzle (single barrier); B streams direct from L2 (layout = 16
// contiguous 64B lines per dwordx4, verified r5/r7), double-buffered (fine-grained vmcnt).
__device__ __forceinline__ void gld16(const void* g, void* l) {
  __builtin_amdgcn_global_load_lds((const __attribute__((address_space(1))) void*)g,
                                   (__attribute__((address_space(3))) void*)l,
                                   16, 0, 0);
}

__global__ __launch_bounds__(256, 5) void k_gemm(
    const unsigned short* __restrict__ Abf, const unsigned short* __restrict__ Bbf,
    const float* __restrict__ thr,
    float* __restrict__ pmax, float* __restrict__ psum, uint32_t* __restrict__ pcnt,
    float* __restrict__ cmax, float* __restrict__ csum) {
  __shared__ __align__(16) unsigned short As[32 * 256];   // 16 KB, swizzled full-K A tile
  __shared__ float4   thrS[32];
  __shared__ float    rowMw[4][32], rowEw[4][32];
  __shared__ uint32_t rowCw[4][32];

  const int ct = blockIdx.x, rt = blockIdx.y;
  const int row0 = rt * 32, col0 = ct * 128;
  const int tid = threadIdx.x;
  const int l = tid & 63, w = tid >> 6;
  const int quad = l >> 4, nl = l & 15;

  if (tid < 32) thrS[tid] = ((const float4*)thr)[row0 + tid];

  // stage A once: 16 groups of 1024 B; group g = (rowset rs = g>>2, k-span ks = g&3).
  // Lane l = lr*8+lc writes 16B chunk (lc^lr) of row lr at slot l*16.
  const int lr = l >> 3, lc7 = l & 7, sc = lc7 ^ lr;
#pragma unroll
  for (int it = 0; it < 4; ++it) {
    int g = w * 4 + it;
    int rs = g >> 2, ks = g & 3;
    const unsigned short* ga = Abf + (size_t)(row0 + rs * 8 + lr) * D_K + ks * 64 + sc * 8;
    gld16(ga, (char*)As + g * 1024);
  }

  f32x4 acc[2][2];
#pragma unroll
  for (int i = 0; i < 2; ++i)
#pragma unroll
    for (int j = 0; j < 2; ++j) acc[i][j] = {0.f, 0.f, 0.f, 0.f};

  // B pointers: col = col0 + w*32 + j*16 + nl, k = quad*8 (+ imm chunk offsets)
  const unsigned short* pB[2];
#pragma unroll
  for (int j = 0; j < 2; ++j)
    pB[j] = Bbf + (size_t)(col0 + w * 32 + j * 16 + nl) * D_K + quad * 8;

  // af LDS byte-offsets: addr(i,c) = (c>>1)*1024 + (c&1 ? baseO : baseE)[i]
  int aoffE[2], aoffO[2];
#pragma unroll
  for (int i = 0; i < 2; ++i) {
    int r = i * 16 + nl, rs = r >> 3, rb = r & 7;
    aoffE[i] = rs * 4096 + rb * 128 + ((quad ^ rb) << 4);
    aoffO[i] = rs * 4096 + rb * 128 + (((4 | quad) ^ rb) << 4);
  }

  __syncthreads();   // the ONLY barrier before the epilogue

  bf16x8 bv[2][2];
#pragma unroll
  for (int j = 0; j < 2; ++j) bv[0][j] = *(const bf16x8*)(pB[j]);

#pragma unroll
  for (int c = 0; c < 8; ++c) {                 // 8 chunks of K=32
    const int cur = c & 1;
    if (c < 7) {
#pragma unroll
      for (int j = 0; j < 2; ++j)
        bv[cur ^ 1][j] = *(const bf16x8*)(pB[j] + (c + 1) * 32);
    }
    bf16x8 af[2];
#pragma unroll
    for (int i = 0; i < 2; ++i)
      af[i] = *(const bf16x8*)((const char*)As + (c >> 1) * 1024
                               + ((c & 1) ? aoffO[i] : aoffE[i]));
#pragma unroll
    for (int i = 0; i < 2; ++i)
#pragma unroll
      for (int j = 0; j < 2; ++j)
        acc[i][j] = __builtin_amdgcn_mfma_f32_16x16x32_bf16(af[i], bv[cur][j],
                                                            acc[i][j], 0, 0, 0);
  }

  // ================= epilogue (scores in log2 domain) =================
  // C/D layout: col = nl, row = quad*4 + reg. Per-row/per-col maxes mandatory
  // (shared max underflows exp2 -> log(0) downstream — r2/r3 bug).

  uint32_t cnt[2][4];
#pragma unroll
  for (int i = 0; i < 2; ++i)
#pragma unroll
    for (int r = 0; r < 4; ++r) {
      float4 th = thrS[i * 16 + quad * 4 + r];
      uint32_t c = 0;
#pragma unroll
      for (int j = 0; j < 2; ++j) {
        float s = acc[i][j][r];
        c += (uint32_t)(s > th.x);
        c += (uint32_t)(s > th.y) << 8;
        c += (uint32_t)(s > th.z) << 16;
        c += (uint32_t)(s > th.w) << 24;
      }
      cnt[i][r] = c;
    }

  // row partials (wave's 32-col strip): per-row max, exp2-sum, count
#pragma unroll
  for (int i = 0; i < 2; ++i)
#pragma unroll
    for (int r = 0; r < 4; ++r) {
      float a0 = acc[i][0][r], a1 = acc[i][1][r];
      float m = fmaxf(a0, a1);
#pragma unroll
      for (int d = 1; d < 16; d <<= 1) m = fmaxf(m, __shfl_xor(m, d));
      float e = EXP2F(a0 - m) + EXP2F(a1 - m);
      uint32_t c = cnt[i][r];
#pragma unroll
      for (int d = 1; d < 16; d <<= 1) { e += __shfl_xor(e, d); c += __shfl_xor(c, d); }
      if (nl == 0) {
        int row = i * 16 + quad * 4 + r;
        rowMw[w][row] = m; rowEw[w][row] = e; rowCw[w][row] = c;   // fields <= 32, no ovf
      }
    }

  // col partials: whole 32-row column lives in this wave -> direct global write
#pragma unroll
  for (int j = 0; j < 2; ++j) {
    float m = -3.0e38f;
#pragma unroll
    for (int i = 0; i < 2; ++i)
#pragma unroll
      for (int r = 0; r < 4; ++r) m = fmaxf(m, acc[i][j][r]);
    m = fmaxf(m, __shfl_xor(m, 16));
    m = fmaxf(m, __shfl_xor(m, 32));
    float e = 0.f;
#pragma unroll
    for (int i = 0; i < 2; ++i)
#pragma unroll
      for (int r = 0; r < 4; ++r) e += EXP2F(acc[i][j][r] - m);
    e += __shfl_xor(e, 16);
    e += __shfl_xor(e, 32);
    if (quad == 0) {
      int colg = col0 + w * 32 + j * 16 + nl;
      size_t gi = (size_t)rt * NT + colg;
      cmax[gi] = m; csum[gi] = e;
    }
  }
  __syncthreads();

  // combine the 4 col-strips per row (packed counts: 4x32 = 128 max, fits 8-bit fields)
  if (tid < 32) {
    float M0 = rowMw[0][tid], M1 = rowMw[1][tid], M2 = rowMw[2][tid], M3 = rowMw[3][tid];
    float Mx = fmaxf(fmaxf(M0, M1), fmaxf(M2, M3));
    float Sx = rowEw[0][tid] * EXP2F(M0 - Mx) + rowEw[1][tid] * EXP2F(M1 - Mx)
             + rowEw[2][tid] * EXP2F(M2 - Mx) + rowEw[3][tid] * EXP2F(M3 - Mx);
    uint32_t C = rowCw[0][tid] + rowCw[1][tid] + rowCw[2][tid] + rowCw[3][tid];
    size_t gi = (size_t)ct * N_V + row0 + tid;
    pmax[gi] = Mx; psum[gi] = Sx; pcnt[gi] = C;
  }
}

// ---------------- C: fused row (128 partials) + col (128 partials) reductions --------------
__global__ void k_red(const float* __restrict__ pmax, const float* __restrict__ psum,
                      const uint32_t* __restrict__ pcnt,
                      const float* __restrict__ cmax, const float* __restrict__ csum,
                      float* __restrict__ rowm, float* __restrict__ rows_,
                      uint4* __restrict__ rcnt,
                      float* __restrict__ colm, float* __restrict__ cols) {
  __shared__ float Lm[4][64], Ls[4][64];
  __shared__ uint4 Lc[4][64];
  __shared__ float Cm[2][128], Cs[2][128];
  const int bid = blockIdx.x, tid = threadIdx.x;
  if (bid < 64) {                      // rows: 64 blocks x 64 rows, 128 partials each
    int l = tid & 63, w = tid >> 6;
    int row = bid * 64 + l;
    float M = -3.0e38f, S = 0.f;
    uint32_t c0 = 0, c1 = 0, c2 = 0, c3 = 0;
    for (int k = 0; k < 32; ++k) {
      size_t idx = (size_t)(w * 32 + k) * N_V + row;
      float m = pmax[idx], s = psum[idx];
      uint32_t cc = pcnt[idx];
      float nM = fmaxf(M, m);
      S = S * EXP2F(M - nM) + s * EXP2F(m - nM);
      M = nM;
      c0 += cc & 0xffu; c1 += (cc >> 8) & 0xffu;
      c2 += (cc >> 16) & 0xffu; c3 += cc >> 24;
    }
    Lm[w][l] = M; Ls[w][l] = S; Lc[w][l] = make_uint4(c0, c1, c2, c3);
    __syncthreads();
    if (tid < 64) {
      float Mx = Lm[0][tid], Sx = Ls[0][tid];
      uint4 C = Lc[0][tid];
#pragma unroll
      for (int ww = 1; ww < 4; ++ww) {
        float m = Lm[ww][tid], s = Ls[ww][tid];
        float nM = fmaxf(Mx, m);
        Sx = Sx * EXP2F(Mx - nM) + s * EXP2F(m - nM);
        Mx = nM;
        uint4 cc = Lc[ww][tid];
        C.x += cc.x; C.y += cc.y; C.z += cc.z; C.w += cc.w;
      }
      int r = bid * 64 + tid;
      rowm[r] = Mx; rows_[r] = Sx; rcnt[r] = C;
    }
  } else {                             // cols: 128 blocks x 128 cols, 128 partials each
    int cb = bid - 64;
    int c = tid & 127, h = tid >> 7;
    int col = cb * 128 + c;
    float M = -3.0e38f, S = 0.f;
    for (int k = 0; k < 64; ++k) {
      size_t idx = (size_t)(h * 64 + k) * NT + col;
      float m = cmax[idx], s = csum[idx];
      float nM = fmaxf(M, m);
      S = S * EXP2F(M - nM) + s * EXP2F(m - nM);
      M = nM;
    }
    Cm[h][c] = M; Cs[h][c] = S;
    __syncthreads();
    if (tid < 128) {
      float M0 = Cm[0][tid], S0 = Cs[0][tid];
      float M1 = Cm[1][tid], S1 = Cs[1][tid];
      float Mx = fmaxf(M0, M1);
      float Sx = S0 * EXP2F(M0 - Mx) + S1 * EXP2F(M1 - Mx);
      int cg = cb * 128 + tid;
      colm[cg] = Mx; cols[cg] = Sx;
    }
  }
}

// ---------------- D: combine per row, loss + metrics, atomic means -------------------------
__global__ void k_final(const float* __restrict__ rowm, const float* __restrict__ rows_,
                        const uint4* __restrict__ rcnt, const float* __restrict__ nom,
                        const float* __restrict__ colm, const float* __restrict__ cols,
                        float* __restrict__ out) {
  int row = blockIdx.x * 256 + threadIdx.x;
  float M = rowm[row], S = rows_[row];
  float cm0 = colm[row * 4 + 0], cm1 = colm[row * 4 + 1];
  float cm2 = colm[row * 4 + 2], cm3 = colm[row * 4 + 3];
  float cs0 = cols[row * 4 + 0], cs1 = cols[row * 4 + 1];
  float cs2 = cols[row * 4 + 2], cs3 = cols[row * 4 + 3];
  float Mp = fmaxf(M, fmaxf(fmaxf(cm0, cm1), fmaxf(cm2, cm3)));
  float tot = S * EXP2F(M - Mp)
            + cs0 * EXP2F(cm0 - Mp) + cs1 * EXP2F(cm1 - Mp)
            + cs2 * EXP2F(cm2 - Mp) + cs3 * EXP2F(cm3 - Mp);
  // scores in log2 domain: natural-log LSE = LN2 * (Mp + log2(tot))
  float ll = LN2 * (Mp + __log2f(tot)) - nom[row];
  uint4 c = rcnt[row];
  float ar  = (float)(c.x + c.y + c.z + c.w) * 0.25f;
  float r1  = (float)((c.x < 1u) + (c.y < 1u) + (c.z < 1u) + (c.w < 1u)) * 0.25f;
  float r5  = (float)((c.x < 5u) + (c.y < 5u) + (c.z < 5u) + (c.w < 5u)) * 0.25f;
  float r10 = (float)((c.x < 10u) + (c.y < 10u) + (c.z < 10u) + (c.w < 10u)) * 0.25f;
  float vals[5] = {ll, r1, r5, r10, ar};
  int l = threadIdx.x & 63;
#pragma unroll
  for (int k = 0; k < 5; ++k) {
    float v = vals[k];
#pragma unroll
    for (int d = 1; d < 64; d <<= 1) v += __shfl_xor(v, d);
    if (l == 0) atomicAdd(&out[k], v * (1.0f / N_V));
  }
}

extern "C" void kernel_launch(void* const* d_in, const int* in_sizes, int n_in,
                              void* d_out, int out_size, void* d_ws, size_t ws_size,
                              hipStream_t stream) {
  const float* v = (const float*)d_in[0];
  const float* t = (const float*)d_in[1];
  char* p = (char*)d_ws;
  unsigned short* Abf = (unsigned short*)p; p += (size_t)N_V * D_K * 2;
  unsigned short* Bbf = (unsigned short*)p; p += (size_t)NT * D_K * 2;
  float* thr  = (float*)p;    p += (size_t)N_V * 4 * 4;
  float* nom  = (float*)p;    p += (size_t)N_V * 4;
  float* pmax = (float*)p;    p += (size_t)128 * N_V * 4;
  float* psum = (float*)p;    p += (size_t)128 * N_V * 4;
  uint32_t* pcnt = (uint32_t*)p; p += (size_t)128 * N_V * 4;
  float* cmaxp = (float*)p;   p += (size_t)128 * NT * 4;
  float* csump = (float*)p;   p += (size_t)128 * NT * 4;
  float* rowm = (float*)p;    p += (size_t)N_V * 4;
  float* rows_ = (float*)p;   p += (size_t)N_V * 4;
  uint4* rcnt = (uint4*)p;    p += (size_t)N_V * 16;
  float* colm = (float*)p;    p += (size_t)NT * 4;
  float* cols = (float*)p;    p += (size_t)NT * 4;
  // total ws: ~33 MB

  k_prep<<<N_V / 4, 256, 0, stream>>>(v, t, Abf, Bbf, thr, nom, (float*)d_out);
  dim3 g(NT / 128, N_V / 32);                     // ct x rt = 128 x 128
  k_gemm<<<g, 256, 0, stream>>>(Abf, Bbf, thr, pmax, psum, pcnt, cmaxp, csump);
  k_red<<<64 + NT / 128, 256, 0, stream>>>(pmax, psum, pcnt, cmaxp, csump,
                                           rowm, rows_, rcnt, colm, cols);
  k_final<<<N_V / 256, 256, 0, stream>>>(rowm, rows_, rcnt, nom, colm, cols, (float*)d_out);
}